// Round 7
// baseline (598.250 us; speedup 1.0000x reference)
//
#include <hip/hip_runtime.h>
#include <hip/hip_cooperative_groups.h>
#include <math.h>

namespace cg = cooperative_groups;

#define NN 8192
#define TILE 64
#define NB (NN / TILE)              // 128 tile rows/cols
#define NPAIRS (NB * (NB + 1) / 2)  // 8256 upper-tri tile pairs
#define FGRID 1024                  // 4 blocks/CU x 256 CUs, co-resident

typedef float floatx4 __attribute__((ext_vector_type(4)));

// sym(i,j) = relu((A[i][j]+A[j][i])/2) is symmetric; output is symmetric.
// One cooperative kernel: phase 1 accumulates rowsums over all upper-tri
// tile pairs (grid-stride), grid.sync(), phase 2 normalizes + writes both
// output tiles per pair. Phase 2 walks each block's pairs in REVERSE so the
// most recently streamed A tiles (L3-resident; A = exactly 256 MiB = L3
// capacity) are re-read first. out stores are nontemporal so they don't
// evict A from L3.

__device__ inline void decode_pair(int k, int& bi, int& bj) {
    int j = (int)((sqrtf(8.0f * (float)k + 1.0f) - 1.0f) * 0.5f);
    while ((j + 1) * (j + 2) / 2 <= k) ++j;   // fp rounding fix-up
    while (j * (j + 1) / 2 > k) --j;
    bj = j;
    bi = k - j * (j + 1) / 2;
}

__global__ __launch_bounds__(256, 4) void fused_kernel(const float* __restrict__ A,
                                                       float* __restrict__ rowsum,
                                                       float* __restrict__ out) {
    __shared__ float lt[TILE][TILE + 1];
    __shared__ float cs[TILE];
    __shared__ float ri[TILE];
    __shared__ float rj[TILE];

    const int t  = threadIdx.x;
    const int lc = t & 15;                     // 0..15 : group of 4 columns
    const int lr = t >> 4;                     // 0..15 : row in each pass

    // ---------------- Phase 1: rowsum ------------------------------------
    for (int k = blockIdx.x; k < NPAIRS; k += FGRID) {
        int bi, bj;
        decode_pair(k, bi, bj);
        const int gi0 = bi * TILE, gj0 = bj * TILE;

        floatx4 va[4];
#pragma unroll
        for (int p = 0; p < 4; ++p) {
            const int r = lr + 16 * p;
            va[p] = *(const floatx4*)&A[(size_t)(gi0 + r) * NN + gj0 + lc * 4];
            const floatx4 vb = *(const floatx4*)&A[(size_t)(gj0 + r) * NN + gi0 + lc * 4];
            lt[r][lc * 4 + 0] = vb.x; lt[r][lc * 4 + 1] = vb.y;
            lt[r][lc * 4 + 2] = vb.z; lt[r][lc * 4 + 3] = vb.w;
        }
        if (t < TILE) cs[t] = 0.0f;
        __syncthreads();

        float colpart[4] = {0.f, 0.f, 0.f, 0.f};
#pragma unroll
        for (int p = 0; p < 4; ++p) {
            const int r = lr + 16 * p;
            const float av[4] = {va[p].x, va[p].y, va[p].z, va[p].w};
            float s = 0.0f;
#pragma unroll
            for (int u = 0; u < 4; ++u) {
                const int c = lc * 4 + u;
                const float v = fmaxf((av[u] + lt[c][r]) * 0.5f, 0.0f);
                s += v;
                colpart[u] += v;
            }
            s += __shfl_xor(s, 1);
            s += __shfl_xor(s, 2);
            s += __shfl_xor(s, 4);
            s += __shfl_xor(s, 8);
            if (lc == 0) atomicAdd(&rowsum[gi0 + r], s);
        }

        if (bi != bj) {
#pragma unroll
            for (int u = 0; u < 4; ++u) {
                colpart[u] += __shfl_xor(colpart[u], 16);
                colpart[u] += __shfl_xor(colpart[u], 32);
            }
            if ((t & 48) == 0) {
#pragma unroll
                for (int u = 0; u < 4; ++u) atomicAdd(&cs[lc * 4 + u], colpart[u]);
            }
            __syncthreads();
            if (t < TILE) atomicAdd(&rowsum[gj0 + t], cs[t]);
        }
        __syncthreads();                       // protect lt/cs reuse
    }

    cg::this_grid().sync();

    // ---------------- Phase 2: normalize + write (reverse order) ---------
    for (int k = NPAIRS - 1 - (int)blockIdx.x; k >= 0; k -= FGRID) {
        int bi, bj;
        decode_pair(k, bi, bj);
        const int gi0 = bi * TILE, gj0 = bj * TILE;

        floatx4 va[4], vb[4];
#pragma unroll
        for (int p = 0; p < 4; ++p) {
            const int r = lr + 16 * p;
            va[p] = *(const floatx4*)&A[(size_t)(gi0 + r) * NN + gj0 + lc * 4];
            vb[p] = *(const floatx4*)&A[(size_t)(gj0 + r) * NN + gi0 + lc * 4];
            lt[r][lc * 4 + 0] = vb[p].x; lt[r][lc * 4 + 1] = vb[p].y;
            lt[r][lc * 4 + 2] = vb[p].z; lt[r][lc * 4 + 3] = vb[p].w;
        }
        if (t < TILE) {
            ri[t] = rsqrtf(rowsum[gi0 + t] + 1.0f);
        } else if (t < 2 * TILE) {
            rj[t - TILE] = rsqrtf(rowsum[gj0 + t - TILE] + 1.0f);
        }
        __syncthreads();

        // Stage A: tile (bi,bj), coalesced NT writes
#pragma unroll
        for (int p = 0; p < 4; ++p) {
            const int r  = lr + 16 * p;
            const int gi = gi0 + r;
            const float av[4] = {va[p].x, va[p].y, va[p].z, va[p].w};
            floatx4 o;
#pragma unroll
            for (int u = 0; u < 4; ++u) {
                const int c = lc * 4 + u;
                float v = fmaxf((av[u] + lt[c][r]) * 0.5f, 0.0f);
                if (gi == gj0 + c) v += 1.0f;
                o[u] = v * ri[r] * rj[c];
            }
            __builtin_nontemporal_store(o, (floatx4*)&out[(size_t)gi * NN + gj0 + lc * 4]);
        }

        // Stage B: transposed tile (bj,bi), coalesced NT writes
        if (bi != bj) {
            __syncthreads();                   // stage-A lt reads done
#pragma unroll
            for (int p = 0; p < 4; ++p) {
                const int r = lr + 16 * p;
                lt[r][lc * 4 + 0] = va[p].x; lt[r][lc * 4 + 1] = va[p].y;
                lt[r][lc * 4 + 2] = va[p].z; lt[r][lc * 4 + 3] = va[p].w;
            }
            __syncthreads();
#pragma unroll
            for (int p = 0; p < 4; ++p) {
                const int r2 = lr + 16 * p;
                const float bv[4] = {vb[p].x, vb[p].y, vb[p].z, vb[p].w};
                floatx4 o;
#pragma unroll
                for (int u = 0; u < 4; ++u) {
                    const int c2 = lc * 4 + u;
                    const float v = fmaxf((bv[u] + lt[c2][r2]) * 0.5f, 0.0f);
                    o[u] = v * rj[r2] * ri[c2];
                }
                __builtin_nontemporal_store(o, (floatx4*)&out[(size_t)(gj0 + r2) * NN + gi0 + lc * 4]);
            }
        }
        __syncthreads();                       // protect lt reuse
    }
}

// ---------------------------------------------------------------------------
// Fallback path: exact R5 two-kernel version (known-good, 496 us).
// ---------------------------------------------------------------------------
__global__ __launch_bounds__(256) void rowsum_kernel(const float* __restrict__ A,
                                                     float* __restrict__ rowsum) {
    const int bi = blockIdx.y, bj = blockIdx.x;
    if (bj < bi) return;

    __shared__ float lt[TILE][TILE + 1];
    __shared__ float cs[TILE];

    const int gi0 = bi * TILE, gj0 = bj * TILE;
    const int t  = threadIdx.x;
    const int lc = t & 15;
    const int lr = t >> 4;

    floatx4 va[4];
#pragma unroll
    for (int p = 0; p < 4; ++p) {
        const int r = lr + 16 * p;
        va[p] = *(const floatx4*)&A[(size_t)(gi0 + r) * NN + gj0 + lc * 4];
        const floatx4 vb = *(const floatx4*)&A[(size_t)(gj0 + r) * NN + gi0 + lc * 4];
        lt[r][lc * 4 + 0] = vb.x; lt[r][lc * 4 + 1] = vb.y;
        lt[r][lc * 4 + 2] = vb.z; lt[r][lc * 4 + 3] = vb.w;
    }
    if (t < TILE) cs[t] = 0.0f;
    __syncthreads();

    float colpart[4] = {0.f, 0.f, 0.f, 0.f};
#pragma unroll
    for (int p = 0; p < 4; ++p) {
        const int r = lr + 16 * p;
        const float av[4] = {va[p].x, va[p].y, va[p].z, va[p].w};
        float s = 0.0f;
#pragma unroll
        for (int u = 0; u < 4; ++u) {
            const int c = lc * 4 + u;
            const float v = fmaxf((av[u] + lt[c][r]) * 0.5f, 0.0f);
            s += v;
            colpart[u] += v;
        }
        s += __shfl_xor(s, 1);
        s += __shfl_xor(s, 2);
        s += __shfl_xor(s, 4);
        s += __shfl_xor(s, 8);
        if (lc == 0) atomicAdd(&rowsum[gi0 + r], s);
    }

    if (bi != bj) {
#pragma unroll
        for (int u = 0; u < 4; ++u) {
            colpart[u] += __shfl_xor(colpart[u], 16);
            colpart[u] += __shfl_xor(colpart[u], 32);
        }
        if ((t & 48) == 0) {
#pragma unroll
            for (int u = 0; u < 4; ++u) atomicAdd(&cs[lc * 4 + u], colpart[u]);
        }
        __syncthreads();
        if (t < TILE) atomicAdd(&rowsum[gj0 + t], cs[t]);
    }
}

__global__ __launch_bounds__(256) void normalize_kernel(const float* __restrict__ A,
                                                        const float* __restrict__ rowsum,
                                                        float* __restrict__ out) {
    const int bi = NB - 1 - (int)blockIdx.y;
    const int bj = NB - 1 - (int)blockIdx.x;
    if (bj < bi) return;

    __shared__ float lt[TILE][TILE + 1];
    __shared__ float ri[TILE];
    __shared__ float rj[TILE];

    const int gi0 = bi * TILE, gj0 = bj * TILE;
    const int t  = threadIdx.x;
    const int lc = t & 15;
    const int lr = t >> 4;

    floatx4 va[4], vb[4];
#pragma unroll
    for (int p = 0; p < 4; ++p) {
        const int r = lr + 16 * p;
        va[p] = *(const floatx4*)&A[(size_t)(gi0 + r) * NN + gj0 + lc * 4];
        vb[p] = *(const floatx4*)&A[(size_t)(gj0 + r) * NN + gi0 + lc * 4];
        lt[r][lc * 4 + 0] = vb[p].x; lt[r][lc * 4 + 1] = vb[p].y;
        lt[r][lc * 4 + 2] = vb[p].z; lt[r][lc * 4 + 3] = vb[p].w;
    }
    if (t < TILE) {
        ri[t] = rsqrtf(rowsum[gi0 + t] + 1.0f);
    } else if (t < 2 * TILE) {
        rj[t - TILE] = rsqrtf(rowsum[gj0 + t - TILE] + 1.0f);
    }
    __syncthreads();

#pragma unroll
    for (int p = 0; p < 4; ++p) {
        const int r  = lr + 16 * p;
        const int gi = gi0 + r;
        const float av[4] = {va[p].x, va[p].y, va[p].z, va[p].w};
        floatx4 o;
#pragma unroll
        for (int u = 0; u < 4; ++u) {
            const int c = lc * 4 + u;
            float v = fmaxf((av[u] + lt[c][r]) * 0.5f, 0.0f);
            if (gi == gj0 + c) v += 1.0f;
            o[u] = v * ri[r] * rj[c];
        }
        __builtin_nontemporal_store(o, (floatx4*)&out[(size_t)gi * NN + gj0 + lc * 4]);
    }

    if (bi != bj) {
        __syncthreads();
#pragma unroll
        for (int p = 0; p < 4; ++p) {
            const int r = lr + 16 * p;
            lt[r][lc * 4 + 0] = va[p].x; lt[r][lc * 4 + 1] = va[p].y;
            lt[r][lc * 4 + 2] = va[p].z; lt[r][lc * 4 + 3] = va[p].w;
        }
        __syncthreads();
#pragma unroll
        for (int p = 0; p < 4; ++p) {
            const int r2 = lr + 16 * p;
            const float bv[4] = {vb[p].x, vb[p].y, vb[p].z, vb[p].w};
            floatx4 o;
#pragma unroll
            for (int u = 0; u < 4; ++u) {
                const int c2 = lc * 4 + u;
                const float v = fmaxf((bv[u] + lt[c2][r2]) * 0.5f, 0.0f);
                o[u] = v * rj[r2] * ri[c2];
            }
            __builtin_nontemporal_store(o, (floatx4*)&out[(size_t)(gj0 + r2) * NN + gi0 + lc * 4]);
        }
    }
}

extern "C" void kernel_launch(void* const* d_in, const int* in_sizes, int n_in,
                              void* d_out, int out_size, void* d_ws, size_t ws_size,
                              hipStream_t stream) {
    const float* A   = (const float*)d_in[0];
    float*       out = (float*)d_out;
    float*       rowsum = (float*)d_ws;   // NN floats = 32 KB

    (void)hipMemsetAsync(rowsum, 0, NN * sizeof(float), stream);

    void* kargs[] = { (void*)&A, (void*)&rowsum, (void*)&out };
    hipError_t err = hipLaunchCooperativeKernel((const void*)fused_kernel,
                                                dim3(FGRID), dim3(256),
                                                kargs, 0, stream);
    if (err != hipSuccess) {
        // Fallback: known-good two-kernel path.
        dim3 grid(NB, NB);
        rowsum_kernel<<<grid, 256, 0, stream>>>(A, rowsum);
        normalize_kernel<<<grid, 256, 0, stream>>>(A, rowsum, out);
    }
}